// Round 11
// baseline (10841.885 us; speedup 1.0000x reference)
//
#include <hip/hip_runtime.h>

#define BB 128
#define TT 1024
#define II 256
#define HH 512
#define OO 256
#define KK 768

typedef _Float16 half8 __attribute__((ext_vector_type(8)));
typedef _Float16 half4v __attribute__((ext_vector_type(4)));
typedef float f32x4 __attribute__((ext_vector_type(4)));
typedef unsigned long long u64_t;
typedef u64_t u64x2 __attribute__((ext_vector_type(2)));

__device__ __forceinline__ float sigm(float x) { return 1.f / (1.f + __expf(-x)); }
__device__ __forceinline__ float tanhfast(float x) {
  float e = __expf(-2.f * fabsf(x));
  return copysignf((1.f - e) / (1.f + e), x);
}

// ---- one-time: W -> fp16 fragment-linear, QUAD-INTERLEAVED (R9-proven layout) ----
// tile (0..127) covers 16 B-cols = 4 units x 4 gates: col c = lu*4 + g, unit = tile*4+lu.
// W16[((tile*24 + ks)*64 + lane)*8]; lane = q*16 + r holds B[col r][ks*32 + q*8 ..+8].
__global__ void __launch_bounds__(64)
prep_w(const float* __restrict__ Wf, const float* __restrict__ Wi,
       const float* __restrict__ Wc, const float* __restrict__ Wo,
       _Float16* __restrict__ W16)
{
  const int bid = blockIdx.x;          // tile*24 + ks
  const int ks = bid % 24, tile = bid / 24;
  const int lane = threadIdx.x;
  const int r = lane & 15, q = lane >> 4;
  const int lu = r >> 2, g = r & 3;
  const int unit = tile * 4 + lu;
  const float* Wg = (g == 0) ? Wf : (g == 1) ? Wi : (g == 2) ? Wc : Wo;
  const float* src = Wg + (size_t)unit * KK + ks * 32 + q * 8;
  float4 w0 = *(const float4*)src;
  float4 w1 = *(const float4*)(src + 4);
  half8 h;
  h[0] = (_Float16)w0.x; h[1] = (_Float16)w0.y; h[2] = (_Float16)w0.z; h[3] = (_Float16)w0.w;
  h[4] = (_Float16)w1.x; h[5] = (_Float16)w1.y; h[6] = (_Float16)w1.z; h[7] = (_Float16)w1.w;
  *(half8*)(W16 + ((size_t)bid * 64 + lane) * 8) = h;
}

// ---- one-time: x [B][T][I] fp32 -> x16 [T][B][I] fp16 ----
__global__ void __launch_bounds__(256)
prep_x(const float* __restrict__ x, _Float16* __restrict__ x16)
{
  const int t = blockIdx.x;
  for (int i = threadIdx.x; i < BB * II / 4; i += 256) {
    const int b = i >> 6, c4 = (i & 63) * 4;
    float4 v = *(const float4*)(x + ((size_t)b * TT + t) * II + c4);
    half4v h;
    h[0] = (_Float16)v.x; h[1] = (_Float16)v.y; h[2] = (_Float16)v.z; h[3] = (_Float16)v.w;
    *(half4v*)(x16 + ((size_t)t * BB + b) * II + c4) = h;
  }
}

// ---- persistent LSTM, time-staggered half-chains ----
// grid=256 cooperative: 8 pairs x 32 WGs. Pair p owns rows p*16..+16, split into
// half-chains A (rows +0..8) and B (+8..16); phases A:t, B:t, A:t+1, ... While one
// half's h propagates through L3+flags, the WG computes the other half -> exchange
// latency hidden. WG = 16 units (4 waves x 4 units, quad-interleaved gate cols ->
// in-wave shfl transpose, NO pre-LDS exchange). Sync/coherence machinery byte-level
// identical to R10 (proven): relaxed agent atomic payload, sync -> tid0 RELEASE
// flag, relaxed poll + workgroup acquire. 2 syncthreads/phase.
__global__ void __launch_bounds__(256, 1)
lstm_persist(const _Float16* __restrict__ x16, const _Float16* __restrict__ W16,
             const float* __restrict__ bfp, const float* __restrict__ bip,
             const float* __restrict__ bcp, const float* __restrict__ bop,
             const float* __restrict__ Wlin, const float* __restrict__ blin,
             float* __restrict__ out,
             _Float16* __restrict__ hbuf,   // [2][BB][HH] fp16, atomic-only traffic
             int* __restrict__ flags)       // [WG][2] x 64B, zeroed per launch
{
  __shared__ __align__(16) char hsb[8 * 1024];  // h stage [8 rows][512] fp16, XOR-swizzled

  const int gid = blockIdx.x;
  const int p = gid >> 5, ugh = gid & 31;
  const int tid = threadIdx.x;
  const int wn = tid >> 6, lane = tid & 63;
  const int r = lane & 15, q = lane >> 4;
  const int lu = r >> 2, g4 = r & 3;
  const int srow = tid >> 5, sc = tid & 31;      // staging role: row, 16B chunk
  const int rsw = (r & 7) << 4, ssw = (srow & 7) << 4;

  // W fragments: one b128 load each from fragment-linear W16 (tile = ugh*4 + wn)
  half8 wfrag[24];
  {
    const half8* wp = (const half8*)W16 + (size_t)(ugh * 4 + wn) * 24 * 64 + lane;
#pragma unroll
    for (int ks = 0; ks < 24; ++ks) wfrag[ks] = wp[ks * 64];
  }

  const int unit = ugh * 16 + wn * 4 + lu;       // this lane's unit (valid per quad)
  const float bfv = bfp[unit], biv = bip[unit], bcv = bcp[unit], bov = bop[unit];
  float CA = 0.f, CB = 0.f;

  // ================= phase loop: A:0, B:0, A:1, B:1, ... =================
  for (int ph = 0; ph < 2 * TT; ++ph) {
    const int D = ph & 1, t = ph >> 1;

    // x fragments (independent of flags; lanes r>=8 duplicate rows 0..7)
    half8 xa[8];
    {
      const _Float16* xr = x16 + ((size_t)t * BB + p * 16 + D * 8 + (r & 7)) * II + q * 8;
#pragma unroll
      for (int ks = 0; ks < 8; ++ks) xa[ks] = *(const half8*)(xr + ks * 32);
    }

    if (t > 0) {
      // poll this half-chain's 32 producer flags (all waves poll -> no extra sync)
      const int* fp = flags + ((size_t)(p * 32 + (lane & 31)) * 2 + D) * 16;
      for (;;) {
        int v = __hip_atomic_load(fp, __ATOMIC_RELAXED, __HIP_MEMORY_SCOPE_AGENT);
        if (__all(v >= t)) break;
        __builtin_amdgcn_s_sleep(1);
      }
      __builtin_amdgcn_fence(__ATOMIC_ACQUIRE, "workgroup");
      // stage h (8 rows x 1KB) -> conflict-free swizzled LDS (slots sc, sc+32)
      const u64_t* hp = (const u64_t*)(hbuf + ((size_t)(t & 1) * BB +
                                               p * 16 + D * 8 + srow) * HH) + sc * 2;
      u64_t s0 = __hip_atomic_load(hp,      __ATOMIC_RELAXED, __HIP_MEMORY_SCOPE_AGENT);
      u64_t s1 = __hip_atomic_load(hp + 1,  __ATOMIC_RELAXED, __HIP_MEMORY_SCOPE_AGENT);
      u64_t s2 = __hip_atomic_load(hp + 64, __ATOMIC_RELAXED, __HIP_MEMORY_SCOPE_AGENT);
      u64_t s3 = __hip_atomic_load(hp + 65, __ATOMIC_RELAXED, __HIP_MEMORY_SCOPE_AGENT);
      char* db = hsb + srow * 1024 + ((sc * 16) ^ ssw);
      *(u64x2*)db = (u64x2){s0, s1};
      *(u64x2*)(db + 512) = (u64x2){s2, s3};
      __syncthreads();
    }

    // MFMA: pre(16x16) = A(rows, k) x W^T; rows 8..15 are duplicates (discarded)
    f32x4 acc = {0.f, 0.f, 0.f, 0.f};
#pragma unroll
    for (int ks = 0; ks < 8; ++ks)
      acc = __builtin_amdgcn_mfma_f32_16x16x32_f16(xa[ks], wfrag[ks], acc, 0, 0, 0);
    if (t > 0) {
      const char* hrow = hsb + (r & 7) * 1024;
#pragma unroll
      for (int ks = 0; ks < 16; ++ks) {
        half8 a = *(const half8*)(hrow + ((ks * 64 + q * 16) ^ rsw));
        acc = __builtin_amdgcn_mfma_f32_16x16x32_f16(a, wfrag[8 + ks], acc, 0, 0, 0);
      }
    }

    // in-wave 4x4 quad transpose (R9-proven): pg[j] = gate-j preact for
    // (row = q*4 + g4, unit) -- valid when q < 2
    float t1[4], sx[4], pg[4];
#pragma unroll
    for (int i = 0; i < 4; ++i) sx[i] = __shfl_xor(acc[i], 1);
#pragma unroll
    for (int i = 0; i < 4; ++i) t1[i] = ((i & 1) == (g4 & 1)) ? acc[i] : sx[i ^ 1];
#pragma unroll
    for (int i = 0; i < 4; ++i) sx[i] = __shfl_xor(t1[i], 2);
#pragma unroll
    for (int i = 0; i < 4; ++i) pg[i] = ((i & 2) == (g4 & 2)) ? t1[i] : sx[i ^ 2];

    float Cc = D ? CB : CA;
    float Cn = sigm(pg[0] + bfv) * Cc + sigm(pg[1] + biv) * tanhfast(pg[2] + bcv);
    if (D) CB = Cn; else CA = Cn;
    float hn = sigm(pg[3] + bov) * tanhfast(Cn);
    unsigned hv;
    { _Float16 a16 = (_Float16)hn; hv = (unsigned)__builtin_bit_cast(unsigned short, a16); }
    unsigned ov = (unsigned)__shfl_down((int)hv, 4);   // partner: lu+1, same row
    if (q < 2 && !(lu & 1)) {
      size_t ei = ((size_t)((t + 1) & 1) * BB + p * 16 + D * 8 + q * 4 + g4) * HH + unit;
      __hip_atomic_store((unsigned*)hbuf + ei / 2, hv | (ov << 16),
                         __ATOMIC_RELAXED, __HIP_MEMORY_SCOPE_AGENT);
    }
    __syncthreads();  // all waves' h-stores drained before the flag (R10 pattern)
    if (tid == 0)
      __hip_atomic_store(flags + ((size_t)gid * 2 + D) * 16, t + 1,
                         __ATOMIC_RELEASE, __HIP_MEMORY_SCOPE_AGENT);
  }

  // ---- final barrier: both half-chains' h_T published pair-wide ----
#pragma unroll
  for (int d2 = 0; d2 < 2; ++d2) {
    const int* fp = flags + ((size_t)(p * 32 + (lane & 31)) * 2 + d2) * 16;
    for (;;) {
      int v = __hip_atomic_load(fp, __ATOMIC_RELAXED, __HIP_MEMORY_SCOPE_AGENT);
      if (__all(v >= TT)) break;
      __builtin_amdgcn_s_sleep(1);
    }
  }
  __builtin_amdgcn_fence(__ATOMIC_ACQUIRE, "workgroup");
  __syncthreads();

  // ===== epilogue (pair rows only): out = h_T @ W_lin^T + b_lin =====
  {
    const int row = p * 16 + (ugh >> 1);
    const int o0 = (ugh & 1) * 128;
    // h_T lives in buffer 0 (last write at t=TT-1 -> buffer TT&1 = 0)
    unsigned v = __hip_atomic_load((const unsigned*)hbuf + (size_t)row * (HH / 2) + tid,
                                   __ATOMIC_RELAXED, __HIP_MEMORY_SCOPE_AGENT);
    float* hf = (float*)hsb;
    hf[2 * tid]     = (float)__builtin_bit_cast(_Float16, (unsigned short)(v & 0xffffu));
    hf[2 * tid + 1] = (float)__builtin_bit_cast(_Float16, (unsigned short)(v >> 16));
    __syncthreads();
    if (tid < 128) {
      int o = o0 + tid;
      float a2 = blin[o];
      const float4* wr = (const float4*)(Wlin + (size_t)o * HH);
#pragma unroll 4
      for (int j = 0; j < 128; ++j) {
        float4 wv = wr[j];
        a2 += wv.x * hf[4 * j] + wv.y * hf[4 * j + 1] +
              wv.z * hf[4 * j + 2] + wv.w * hf[4 * j + 3];
      }
      out[(size_t)row * OO + o] = a2;
    }
  }
}

extern "C" void kernel_launch(void* const* d_in, const int* in_sizes, int n_in,
                              void* d_out, int out_size, void* d_ws, size_t ws_size,
                              hipStream_t stream) {
  const float* x    = (const float*)d_in[0];
  const float* Wf   = (const float*)d_in[1];
  const float* bf_  = (const float*)d_in[2];
  const float* Wi   = (const float*)d_in[3];
  const float* bi_  = (const float*)d_in[4];
  const float* Wc   = (const float*)d_in[5];
  const float* bc_  = (const float*)d_in[6];
  const float* Wo   = (const float*)d_in[7];
  const float* bo_  = (const float*)d_in[8];
  const float* Wlin = (const float*)d_in[9];
  const float* blin = (const float*)d_in[10];
  float* out = (float*)d_out;

  // ws: flags [0,32K) | hbuf [64K,320K) | W16 [1M,4M) | x16 [4M,68M)
  // (total 71,303,168 B -- proven sufficient since R5/R6)
  int*      flags = (int*)d_ws;
  _Float16* hbuf  = (_Float16*)((char*)d_ws + 65536);
  _Float16* W16   = (_Float16*)((char*)d_ws + 1048576);
  _Float16* x16   = (_Float16*)((char*)d_ws + 4194304);

  hipMemsetAsync(d_ws, 0, 65536, stream);  // zero barrier flags every launch
  prep_w<<<dim3(128 * 24), dim3(64), 0, stream>>>(Wf, Wi, Wc, Wo, W16);
  prep_x<<<dim3(TT), dim3(256), 0, stream>>>(x, x16);

  void* args[] = {(void*)&x16, (void*)&W16, (void*)&bf_, (void*)&bi_, (void*)&bc_,
                  (void*)&bo_, (void*)&Wlin, (void*)&blin, (void*)&out,
                  (void*)&hbuf, (void*)&flags};
  hipLaunchCooperativeKernel((const void*)lstm_persist, dim3(256), dim3(256),
                             args, 0, stream);
}

// Round 12
// 6781.078 us; speedup vs baseline: 1.5988x; 1.5988x over previous
//
#include <hip/hip_runtime.h>

#define BB 128
#define TT 1024
#define II 256
#define HH 512
#define OO 256
#define KK 768

typedef _Float16 half8 __attribute__((ext_vector_type(8)));
typedef _Float16 half4v __attribute__((ext_vector_type(4)));
typedef float f32x4 __attribute__((ext_vector_type(4)));
typedef unsigned long long u64_t;

__device__ __forceinline__ float sigm(float x) { return 1.f / (1.f + __expf(-x)); }
__device__ __forceinline__ float tanhfast(float x) {
  float e = __expf(-2.f * fabsf(x));
  return copysignf((1.f - e) / (1.f + e), x);
}

// ---- one-time: W -> fp16 fragment-linear, QUAD-INTERLEAVED (R9/R11-proven) ----
// tile t (0..127) covers 16 B-cols: col c = lu*4 + g, unit = tile*4 + lu.
// W16[((tile*24 + ks)*64 + lane)*8]; lane = q*16 + r holds B[col r][ks*32+q*8 ..+8].
__global__ void __launch_bounds__(64)
prep_w(const float* __restrict__ Wf, const float* __restrict__ Wi,
       const float* __restrict__ Wc, const float* __restrict__ Wo,
       _Float16* __restrict__ W16)
{
  const int bid = blockIdx.x;          // tile*24 + ks
  const int ks = bid % 24, tile = bid / 24;
  const int lane = threadIdx.x;
  const int r = lane & 15, q = lane >> 4;
  const int lu = r >> 2, g = r & 3;
  const int unit = tile * 4 + lu;
  const float* Wg = (g == 0) ? Wf : (g == 1) ? Wi : (g == 2) ? Wc : Wo;
  const float* src = Wg + (size_t)unit * KK + ks * 32 + q * 8;
  float4 w0 = *(const float4*)src;
  float4 w1 = *(const float4*)(src + 4);
  half8 h;
  h[0] = (_Float16)w0.x; h[1] = (_Float16)w0.y; h[2] = (_Float16)w0.z; h[3] = (_Float16)w0.w;
  h[4] = (_Float16)w1.x; h[5] = (_Float16)w1.y; h[6] = (_Float16)w1.z; h[7] = (_Float16)w1.w;
  *(half8*)(W16 + ((size_t)bid * 64 + lane) * 8) = h;
}

// ---- one-time: x [B][T][I] fp32 -> x16 [T][B][I] fp16 ----
__global__ void __launch_bounds__(256)
prep_x(const float* __restrict__ x, _Float16* __restrict__ x16)
{
  const int t = blockIdx.x;
  for (int i = threadIdx.x; i < BB * II / 4; i += 256) {
    const int b = i >> 6, c4 = (i & 63) * 4;
    float4 v = *(const float4*)(x + ((size_t)b * TT + t) * II + c4);
    half4v h;
    h[0] = (_Float16)v.x; h[1] = (_Float16)v.y; h[2] = (_Float16)v.z; h[3] = (_Float16)v.w;
    *(half4v*)(x16 + ((size_t)t * BB + b) * II + c4) = h;
  }
}

// ---- persistent LSTM with TAGGED-PAYLOAD exchange ----
// grid=256 cooperative (launch shape identical to R10/R11): 8 domains (16 batch
// rows) x 32 WGs (16 units). W fp16 in registers (96 VGPR, quad-interleaved).
// h word = u32 (epoch<<16 | fp16): producer's atomic store IS the flag;
// consumers poll the exact words they need (relaxed agent u64 loads). Tag and
// value are one single-copy-atomic word -> no fences, no flags, no release
// ordering anywhere. Double-buffer by t&1; the dependency chain guarantees a
// producer can't overwrite epoch e before every consumer WG read epoch e-2.
// memset(0) = tag 0 = h_0 exactly. ONE __syncthreads per step (shfl transpose
// replaces the pre[] LDS exchange; LDS h-stage is double-buffered).
__global__ void __launch_bounds__(256, 1)
lstm_persist(const _Float16* __restrict__ x16, const _Float16* __restrict__ W16,
             const float* __restrict__ bfp, const float* __restrict__ bip,
             const float* __restrict__ bcp, const float* __restrict__ bop,
             const float* __restrict__ Wlin, const float* __restrict__ blin,
             float* __restrict__ out,
             unsigned* __restrict__ hbuf)   // [2][BB][HH] tagged u32, memset 0
{
  __shared__ __align__(16) char hsb[2][16 * 1024];  // staged h [buf][16 rows][512] fp16

  const int gid = blockIdx.x;
  const int p = gid >> 5, ugh = gid & 31;
  const int tid = threadIdx.x;
  const int wn = tid >> 6, lane = tid & 63;
  const int r = lane & 15, q = lane >> 4;
  const int lu = r >> 2, g4 = r & 3;
  const int srow = tid >> 4, schunk = tid & 15;   // staging role: row, 32-unit chunk
  const int rsw = (r & 7) << 4, ssw = (srow & 7) << 4;
  const int scb = schunk * 64;

  // W fragments (one b128 load each; tile = ugh*4 + wn)
  half8 wfrag[24];
  {
    const half8* wp = (const half8*)W16 + (size_t)(ugh * 4 + wn) * 24 * 64 + lane;
#pragma unroll
    for (int ks = 0; ks < 24; ++ks) wfrag[ks] = wp[ks * 64];
  }

  const int unit = ugh * 16 + wn * 4 + lu;        // this lane's (row,unit) after transpose
  const float bfv = bfp[unit], biv = bip[unit], bcv = bcp[unit], bov = bop[unit];
  float C = 0.0f;
  const int arow = p * 16 + r;                    // A (batch) row this lane feeds

  // ================= time loop =================
  for (int t = 0; t < TT; ++t) {
    // x fragments (issued first; latency hides under poll)
    const _Float16* xr = x16 + ((size_t)t * BB + arow) * II + q * 8;
    half8 xa[8];
#pragma unroll
    for (int ks = 0; ks < 8; ++ks) xa[ks] = *(const half8*)(xr + ks * 32);

    const int buf = t & 1;
    if (t > 0) {
      // ---- poll + load this thread's 32 tagged words (16 u64) for h_t ----
      const u64_t* hp = (const u64_t*)(hbuf + ((size_t)buf * BB + p * 16 + srow) * HH)
                        + schunk * 16;
      const u64_t expect = ((u64_t)(unsigned)t << 16) | ((u64_t)(unsigned)t << 48);
      u64_t v[16];
      for (;;) {
        u64_t bad = 0;
#pragma unroll
        for (int j = 0; j < 16; ++j) {
          v[j] = __hip_atomic_load(hp + j, __ATOMIC_RELAXED, __HIP_MEMORY_SCOPE_AGENT);
          bad |= (v[j] ^ expect) & 0xFFFF0000FFFF0000ull;
        }
        if (bad == 0) break;
        __builtin_amdgcn_s_sleep(1);
      }
      // ---- strip tags, pack, write LDS (byte-identical addresses to R10) ----
      char* dst = hsb[buf] + srow * 1024;
#pragma unroll
      for (int j2 = 0; j2 < 8; ++j2) {
        u64_t a = v[2 * j2], b = v[2 * j2 + 1];
        unsigned p0 = (unsigned)(a & 0xffffu) | ((unsigned)(a >> 32) << 16);
        unsigned p1 = (unsigned)(b & 0xffffu) | ((unsigned)(b >> 32) << 16);
        *(u64_t*)(dst + ((scb + j2 * 8) ^ ssw)) = (u64_t)p0 | ((u64_t)p1 << 32);
      }
      __syncthreads();  // the ONLY barrier per step
    }

    // ---- MFMA: D(16x16) = A(16 x 768) * Wtile^T ----
    f32x4 acc = {0.f, 0.f, 0.f, 0.f};
#pragma unroll
    for (int ks = 0; ks < 8; ++ks)
      acc = __builtin_amdgcn_mfma_f32_16x16x32_f16(xa[ks], wfrag[ks], acc, 0, 0, 0);
    if (t > 0) {
      const char* hrow = hsb[buf] + r * 1024;
#pragma unroll
      for (int ks = 0; ks < 16; ++ks) {
        half8 a = *(const half8*)(hrow + ((ks * 64 + q * 16) ^ rsw));
        acc = __builtin_amdgcn_mfma_f32_16x16x32_f16(a, wfrag[8 + ks], acc, 0, 0, 0);
      }
    }

    // ---- in-wave 4x4 quad transpose (R9/R11-proven): pg[j] = gate-j preact
    //      for (row = q*4 + g4, local unit lu); valid on ALL lanes ----
    float t1[4], sx[4], pg[4];
#pragma unroll
    for (int i = 0; i < 4; ++i) sx[i] = __shfl_xor(acc[i], 1);
#pragma unroll
    for (int i = 0; i < 4; ++i) t1[i] = ((i & 1) == (g4 & 1)) ? acc[i] : sx[i ^ 1];
#pragma unroll
    for (int i = 0; i < 4; ++i) sx[i] = __shfl_xor(t1[i], 2);
#pragma unroll
    for (int i = 0; i < 4; ++i) pg[i] = ((i & 2) == (g4 & 2)) ? t1[i] : sx[i ^ 2];

    // ---- gates + state; ONE tagged u32 atomic store per thread ----
    C = sigm(pg[0] + bfv) * C + sigm(pg[1] + biv) * tanhfast(pg[2] + bcv);
    float hn = sigm(pg[3] + bov) * tanhfast(C);
    unsigned hv;
    { _Float16 a16 = (_Float16)hn; hv = (unsigned)__builtin_bit_cast(unsigned short, a16); }
    {
      const int prow = p * 16 + q * 4 + g4;
      unsigned val = ((unsigned)(t + 1) << 16) | hv;
      __hip_atomic_store(hbuf + ((size_t)((t + 1) & 1) * BB + prow) * HH + unit,
                         val, __ATOMIC_RELAXED, __HIP_MEMORY_SCOPE_AGENT);
    }
  }

  // ===== epilogue: poll h_T (tag TT, buffer 0); out = h_T @ W_lin^T + b_lin =====
  {
    const int erow = p * 16 + (ugh >> 1);
    const int o0 = (ugh & 1) * 128;
    float* hf = (float*)hsb;  // 2 KB reuse
    const unsigned* hb = hbuf + (size_t)erow * HH;  // buffer 0
#pragma unroll
    for (int k = 0; k < 2; ++k) {
      int u = tid + k * 256;
      unsigned v;
      for (;;) {
        v = __hip_atomic_load(hb + u, __ATOMIC_RELAXED, __HIP_MEMORY_SCOPE_AGENT);
        if ((v >> 16) == (unsigned)TT) break;
        __builtin_amdgcn_s_sleep(1);
      }
      hf[u] = (float)__builtin_bit_cast(_Float16, (unsigned short)(v & 0xffffu));
    }
    __syncthreads();
    if (tid < 128) {
      int o = o0 + tid;
      float a2 = blin[o];
      const float4* wr = (const float4*)(Wlin + (size_t)o * HH);
#pragma unroll 4
      for (int j = 0; j < 128; ++j) {
        float4 wv = wr[j];
        a2 += wv.x * hf[4 * j] + wv.y * hf[4 * j + 1] +
              wv.z * hf[4 * j + 2] + wv.w * hf[4 * j + 3];
      }
      out[(size_t)erow * OO + o] = a2;
    }
  }
}

extern "C" void kernel_launch(void* const* d_in, const int* in_sizes, int n_in,
                              void* d_out, int out_size, void* d_ws, size_t ws_size,
                              hipStream_t stream) {
  const float* x    = (const float*)d_in[0];
  const float* Wf   = (const float*)d_in[1];
  const float* bf_  = (const float*)d_in[2];
  const float* Wi   = (const float*)d_in[3];
  const float* bi_  = (const float*)d_in[4];
  const float* Wc   = (const float*)d_in[5];
  const float* bc_  = (const float*)d_in[6];
  const float* Wo   = (const float*)d_in[7];
  const float* bo_  = (const float*)d_in[8];
  const float* Wlin = (const float*)d_in[9];
  const float* blin = (const float*)d_in[10];
  float* out = (float*)d_out;

  // ws: hbuf(tagged u32) [64K, 64K+512K) | W16 [1M,4M) | x16 [4M,68M)
  // (within 71,303,168 B, proven sufficient since R5/R6)
  unsigned*  hbuf = (unsigned*)((char*)d_ws + 65536);
  _Float16*  W16  = (_Float16*)((char*)d_ws + 1048576);
  _Float16*  x16  = (_Float16*)((char*)d_ws + 4194304);

  // zero hbuf each launch: tag 0 + value 0 == exactly h_0 (and clears replay tags)
  hipMemsetAsync((char*)d_ws + 65536, 0, 2u * BB * HH * 4u, stream);
  prep_w<<<dim3(128 * 24), dim3(64), 0, stream>>>(Wf, Wi, Wc, Wo, W16);
  prep_x<<<dim3(TT), dim3(256), 0, stream>>>(x, x16);

  void* args[] = {(void*)&x16, (void*)&W16, (void*)&bf_, (void*)&bi_, (void*)&bc_,
                  (void*)&bo_, (void*)&Wlin, (void*)&blin, (void*)&out, (void*)&hbuf};
  hipLaunchCooperativeKernel((const void*)lstm_persist, dim3(256), dim3(256),
                             args, 0, stream);
}

// Round 13
// 4562.946 us; speedup vs baseline: 2.3761x; 1.4861x over previous
//
#include <hip/hip_runtime.h>

#define BB 128
#define TT 1024
#define II 256
#define HH 512
#define OO 256
#define KK 768

typedef _Float16 half8 __attribute__((ext_vector_type(8)));
typedef _Float16 half4v __attribute__((ext_vector_type(4)));
typedef float f32x4 __attribute__((ext_vector_type(4)));
typedef unsigned u32x4 __attribute__((ext_vector_type(4)));
typedef unsigned long long u64_t;

__device__ __forceinline__ float sigm(float x) { return 1.f / (1.f + __expf(-x)); }
__device__ __forceinline__ float tanhfast(float x) {
  float e = __expf(-2.f * fabsf(x));
  return copysignf((1.f - e) / (1.f + e), x);
}

// ---- one-time: W -> fp16 fragment-linear (R12 layout, unchanged) ----
__global__ void __launch_bounds__(64)
prep_w(const float* __restrict__ Wf, const float* __restrict__ Wi,
       const float* __restrict__ Wc, const float* __restrict__ Wo,
       _Float16* __restrict__ W16)
{
  const int bid = blockIdx.x;          // tile*24 + ks
  const int ks = bid % 24, tile = bid / 24;
  const int lane = threadIdx.x;
  const int r = lane & 15, q = lane >> 4;
  const int lu = r >> 2, g = r & 3;
  const int unit = tile * 4 + lu;
  const float* Wg = (g == 0) ? Wf : (g == 1) ? Wi : (g == 2) ? Wc : Wo;
  const float* src = Wg + (size_t)unit * KK + ks * 32 + q * 8;
  float4 w0 = *(const float4*)src;
  float4 w1 = *(const float4*)(src + 4);
  half8 h;
  h[0] = (_Float16)w0.x; h[1] = (_Float16)w0.y; h[2] = (_Float16)w0.z; h[3] = (_Float16)w0.w;
  h[4] = (_Float16)w1.x; h[5] = (_Float16)w1.y; h[6] = (_Float16)w1.z; h[7] = (_Float16)w1.w;
  *(half8*)(W16 + ((size_t)bid * 64 + lane) * 8) = h;
}

// ---- one-time: x [B][T][I] fp32 -> x16 [T][B][I] fp16 (unchanged) ----
__global__ void __launch_bounds__(256)
prep_x(const float* __restrict__ x, _Float16* __restrict__ x16)
{
  const int t = blockIdx.x;
  for (int i = threadIdx.x; i < BB * II / 4; i += 256) {
    const int b = i >> 6, c4 = (i & 63) * 4;
    float4 v = *(const float4*)(x + ((size_t)b * TT + t) * II + c4);
    half4v h;
    h[0] = (_Float16)v.x; h[1] = (_Float16)v.y; h[2] = (_Float16)v.z; h[3] = (_Float16)v.w;
    *(half4v*)(x16 + ((size_t)t * BB + b) * II + c4) = h;
  }
}

__device__ __forceinline__ unsigned pack2(unsigned a, unsigned b) {
  return (a & 0xffffu) | (b << 16);
}
__device__ __forceinline__ unsigned badtag(u32x4 g, unsigned ex) {
  return ((g.x ^ ex) | (g.y ^ ex) | (g.z ^ ex) | (g.w ^ ex)) & 0xFFFF0000u;
}

// ---- persistent LSTM, XCD-local L2 exchange + tagged payload ----
// grid=256 cooperative (R12 shape): 8 domains x 32 WGs; domain p = gid & 7 ->
// all 32 WGs of a domain land on XCD p under round-robin dispatch [m09].
// h word = u32 (epoch<<16 | fp16), R12-proven. Producers DOUBLE-store: plain
// global_store (updates the XCD-local L2 = intra-XCD coherence point) + sc1
// agent atomic (updates L3). Consumers poll the exact payload words they need
// with sc0 loads (bypass L1, hit L2: ~3x lower RT than L3), alternating with
// R12's agent atomic loads as a mapping-independent fallback. No fences, no
// flags in either path (tag rides in the same 4B word).
// Staging writes are conflict-free contiguous ds_write_b128 (swizzle applied
// to the GLOBAL source address, m173). x-part MFMAs run in shadow (accN for
// t+1 computed after the h-store, off the critical chain).
__global__ void __launch_bounds__(256, 1)
lstm_persist(const _Float16* __restrict__ x16, const _Float16* __restrict__ W16,
             const float* __restrict__ bfp, const float* __restrict__ bip,
             const float* __restrict__ bcp, const float* __restrict__ bop,
             const float* __restrict__ Wlin, const float* __restrict__ blin,
             float* __restrict__ out,
             unsigned* __restrict__ hbuf)   // [2][BB][HH] tagged u32, memset 0
{
  __shared__ __align__(16) char hsb[2][16 * 1024];  // staged h [buf][16 rows][512] fp16

  const int gid = blockIdx.x;
  const int p = gid & 7;          // domain == XCD (perf+latency assumption; sc1 fallback covers correctness)
  const int ugh = gid >> 3;       // hidden group 0..31 (16 units)
  const int tid = threadIdx.x;
  const int wn = tid >> 6, lane = tid & 63;
  const int r = lane & 15, q = lane >> 4;
  const int lu = r >> 2, g4 = r & 3;
  const int rsw = (r & 7) << 4;

  // W fragments (R12 layout; tile = ugh*4 + wn)
  half8 wfrag[24];
  {
    const half8* wp = (const half8*)W16 + (size_t)(ugh * 4 + wn) * 24 * 64 + lane;
#pragma unroll
    for (int ks = 0; ks < 24; ++ks) wfrag[ks] = wp[ks * 64];
  }

  const int unit = ugh * 16 + wn * 4 + lu;
  const float bfv = bfp[unit], biv = bip[unit], bcv = bcp[unit], bov = bop[unit];
  float C = 0.0f;
  const int arow = p * 16 + r;    // A (batch) row this lane feeds

  // staging source geometry: group j covers LDS bytes j*4096 + tid*16 (..+16),
  // i.e. row = 4j + wn, units 8*(lane ^ ((4j+wn)&7)) .. +8  (32B tagged)
  int unit0[4];
#pragma unroll
  for (int j = 0; j < 4; ++j) unit0[j] = 8 * (lane ^ ((4 * j + wn) & 7));

  // prologue: accN = x-part for t=0
  f32x4 accN = {0.f, 0.f, 0.f, 0.f};
  {
    const _Float16* xr = x16 + (size_t)arow * II + q * 8;
#pragma unroll
    for (int ks = 0; ks < 8; ++ks) {
      half8 a = *(const half8*)(xr + ks * 32);
      accN = __builtin_amdgcn_mfma_f32_16x16x32_f16(a, wfrag[ks], accN, 0, 0, 0);
    }
  }

  // ================= time loop =================
  for (int t = 0; t < TT; ++t) {
    f32x4 acc = accN;             // x-part (computed in shadow last step)
    const int buf = t & 1;

    if (t > 0) {
      const unsigned ex32 = (unsigned)t << 16;
      const unsigned* b0 = hbuf + ((size_t)(buf * BB + p * 16) + 0 + wn) * HH + unit0[0];
      const unsigned* b1 = hbuf + ((size_t)(buf * BB + p * 16) + 4 + wn) * HH + unit0[1];
      const unsigned* b2 = hbuf + ((size_t)(buf * BB + p * 16) + 8 + wn) * HH + unit0[2];
      const unsigned* b3 = hbuf + ((size_t)(buf * BB + p * 16) + 12 + wn) * HH + unit0[3];
      u32x4 G0, G1, G2, G3, G4, G5, G6, G7;
      for (int it = 0;; ++it) {
        if ((it & 1) == 0) {
          // fast path: XCD-local L2 (sc0 = bypass L1, L2-coherent)
          asm volatile(
            "global_load_dwordx4 %0, %8, off sc0\n\t"
            "global_load_dwordx4 %1, %8, off offset:16 sc0\n\t"
            "global_load_dwordx4 %2, %9, off sc0\n\t"
            "global_load_dwordx4 %3, %9, off offset:16 sc0\n\t"
            "global_load_dwordx4 %4, %10, off sc0\n\t"
            "global_load_dwordx4 %5, %10, off offset:16 sc0\n\t"
            "global_load_dwordx4 %6, %11, off sc0\n\t"
            "global_load_dwordx4 %7, %11, off offset:16 sc0\n\t"
            "s_waitcnt vmcnt(0)"
            : "=&v"(G0), "=&v"(G1), "=&v"(G2), "=&v"(G3),
              "=&v"(G4), "=&v"(G5), "=&v"(G6), "=&v"(G7)
            : "v"(b0), "v"(b1), "v"(b2), "v"(b3)
            : "memory");
        } else {
          // fallback: agent atomics at L3 (R12-proven, mapping-independent)
          const u64_t* pp;
          u64_t a0, a1, a2, a3;
#define LD4(bp, A, B)                                                            \
          pp = (const u64_t*)(bp);                                               \
          a0 = __hip_atomic_load(pp,     __ATOMIC_RELAXED, __HIP_MEMORY_SCOPE_AGENT); \
          a1 = __hip_atomic_load(pp + 1, __ATOMIC_RELAXED, __HIP_MEMORY_SCOPE_AGENT); \
          a2 = __hip_atomic_load(pp + 2, __ATOMIC_RELAXED, __HIP_MEMORY_SCOPE_AGENT); \
          a3 = __hip_atomic_load(pp + 3, __ATOMIC_RELAXED, __HIP_MEMORY_SCOPE_AGENT); \
          A = (u32x4){(unsigned)a0, (unsigned)(a0 >> 32), (unsigned)a1, (unsigned)(a1 >> 32)}; \
          B = (u32x4){(unsigned)a2, (unsigned)(a2 >> 32), (unsigned)a3, (unsigned)(a3 >> 32)};
          LD4(b0, G0, G1) LD4(b1, G2, G3) LD4(b2, G4, G5) LD4(b3, G6, G7)
#undef LD4
        }
        unsigned bad = badtag(G0, ex32) | badtag(G1, ex32) | badtag(G2, ex32) |
                       badtag(G3, ex32) | badtag(G4, ex32) | badtag(G5, ex32) |
                       badtag(G6, ex32) | badtag(G7, ex32);
        if (bad == 0) break;
        __builtin_amdgcn_s_sleep(1);
      }
      // strip tags -> packed fp16; contiguous per-wave b128 writes (conflict-free)
      char* dst = hsb[buf] + tid * 16;
      *(u32x4*)(dst)          = (u32x4){pack2(G0.x, G0.y), pack2(G0.z, G0.w),
                                        pack2(G1.x, G1.y), pack2(G1.z, G1.w)};
      *(u32x4*)(dst + 4096)   = (u32x4){pack2(G2.x, G2.y), pack2(G2.z, G2.w),
                                        pack2(G3.x, G3.y), pack2(G3.z, G3.w)};
      *(u32x4*)(dst + 8192)   = (u32x4){pack2(G4.x, G4.y), pack2(G4.z, G4.w),
                                        pack2(G5.x, G5.y), pack2(G5.z, G5.w)};
      *(u32x4*)(dst + 12288)  = (u32x4){pack2(G6.x, G6.y), pack2(G6.z, G6.w),
                                        pack2(G7.x, G7.y), pack2(G7.z, G7.w)};
      __syncthreads();

      // h-part MFMAs (swizzled read, R12-proven)
      const char* hrow = hsb[buf] + r * 1024;
#pragma unroll
      for (int ks = 0; ks < 16; ++ks) {
        half8 a = *(const half8*)(hrow + ((ks * 64 + q * 16) ^ rsw));
        acc = __builtin_amdgcn_mfma_f32_16x16x32_f16(a, wfrag[8 + ks], acc, 0, 0, 0);
      }
    }

    // in-wave 4x4 quad transpose (R9/R11/R12-proven)
    float t1[4], sx[4], pg[4];
#pragma unroll
    for (int i = 0; i < 4; ++i) sx[i] = __shfl_xor(acc[i], 1);
#pragma unroll
    for (int i = 0; i < 4; ++i) t1[i] = ((i & 1) == (g4 & 1)) ? acc[i] : sx[i ^ 1];
#pragma unroll
    for (int i = 0; i < 4; ++i) sx[i] = __shfl_xor(t1[i], 2);
#pragma unroll
    for (int i = 0; i < 4; ++i) pg[i] = ((i & 2) == (g4 & 2)) ? t1[i] : sx[i ^ 2];

    // gates + state; DOUBLE store: plain (-> local L2) + sc1 atomic (-> L3)
    C = sigm(pg[0] + bfv) * C + sigm(pg[1] + biv) * tanhfast(pg[2] + bcv);
    float hn = sigm(pg[3] + bov) * tanhfast(C);
    unsigned hv;
    { _Float16 a16 = (_Float16)hn; hv = (unsigned)__builtin_bit_cast(unsigned short, a16); }
    {
      unsigned val = ((unsigned)(t + 1) << 16) | hv;
      unsigned* sa = hbuf + ((size_t)(((t + 1) & 1)) * BB + p * 16 + q * 4 + g4) * HH + unit;
      asm volatile("global_store_dword %0, %1, off" :: "v"(sa), "v"(val) : "memory");
      __hip_atomic_store(sa, val, __ATOMIC_RELAXED, __HIP_MEMORY_SCOPE_AGENT);
    }

    // shadow: x-part for t+1 (off the critical chain)
    if (t + 1 < TT) {
      accN = (f32x4){0.f, 0.f, 0.f, 0.f};
      const _Float16* xr = x16 + ((size_t)(t + 1) * BB + arow) * II + q * 8;
#pragma unroll
      for (int ks = 0; ks < 8; ++ks) {
        half8 a = *(const half8*)(xr + ks * 32);
        accN = __builtin_amdgcn_mfma_f32_16x16x32_f16(a, wfrag[ks], accN, 0, 0, 0);
      }
    }
  }

  // ===== epilogue: poll h_T (tag TT, buffer 0) via agent atomics (R12) =====
  {
    const int erow = p * 16 + (ugh >> 1);
    const int o0 = (ugh & 1) * 128;
    float* hf = (float*)hsb;
    const unsigned* hb = hbuf + (size_t)erow * HH;  // buffer 0
#pragma unroll
    for (int k = 0; k < 2; ++k) {
      int u = tid + k * 256;
      unsigned v;
      for (;;) {
        v = __hip_atomic_load(hb + u, __ATOMIC_RELAXED, __HIP_MEMORY_SCOPE_AGENT);
        if ((v >> 16) == (unsigned)TT) break;
        __builtin_amdgcn_s_sleep(1);
      }
      hf[u] = (float)__builtin_bit_cast(_Float16, (unsigned short)(v & 0xffffu));
    }
    __syncthreads();
    if (tid < 128) {
      int o = o0 + tid;
      float a2 = blin[o];
      const float4* wr = (const float4*)(Wlin + (size_t)o * HH);
#pragma unroll 4
      for (int j = 0; j < 128; ++j) {
        float4 wv = wr[j];
        a2 += wv.x * hf[4 * j] + wv.y * hf[4 * j + 1] +
              wv.z * hf[4 * j + 2] + wv.w * hf[4 * j + 3];
      }
      out[(size_t)erow * OO + o] = a2;
    }
  }
}

extern "C" void kernel_launch(void* const* d_in, const int* in_sizes, int n_in,
                              void* d_out, int out_size, void* d_ws, size_t ws_size,
                              hipStream_t stream) {
  const float* x    = (const float*)d_in[0];
  const float* Wf   = (const float*)d_in[1];
  const float* bf_  = (const float*)d_in[2];
  const float* Wi   = (const float*)d_in[3];
  const float* bi_  = (const float*)d_in[4];
  const float* Wc   = (const float*)d_in[5];
  const float* bc_  = (const float*)d_in[6];
  const float* Wo   = (const float*)d_in[7];
  const float* bo_  = (const float*)d_in[8];
  const float* Wlin = (const float*)d_in[9];
  const float* blin = (const float*)d_in[10];
  float* out = (float*)d_out;

  // ws: hbuf(tagged u32) [64K, 64K+512K) | W16 [1M,4M) | x16 [4M,68M)
  unsigned*  hbuf = (unsigned*)((char*)d_ws + 65536);
  _Float16*  W16  = (_Float16*)((char*)d_ws + 1048576);
  _Float16*  x16  = (_Float16*)((char*)d_ws + 4194304);

  hipMemsetAsync((char*)d_ws + 65536, 0, 2u * BB * HH * 4u, stream);
  prep_w<<<dim3(128 * 24), dim3(64), 0, stream>>>(Wf, Wi, Wc, Wo, W16);
  prep_x<<<dim3(TT), dim3(256), 0, stream>>>(x, x16);

  void* args[] = {(void*)&x16, (void*)&W16, (void*)&bf_, (void*)&bi_, (void*)&bc_,
                  (void*)&bo_, (void*)&Wlin, (void*)&blin, (void*)&out, (void*)&hbuf};
  hipLaunchCooperativeKernel((const void*)lstm_persist, dim3(256), dim3(256),
                             args, 0, stream);
}